// Round 1
// 743.548 us; speedup vs baseline: 1.1301x; 1.1301x over previous
//
#include <hip/hip_runtime.h>
#include <math.h>

// Problem constants (reference: N_NODES=50000, F_in=1433, F1=16, F2=7)
#define F_IN 1433
#define F1 16
#define F2 7
#define SCAN_CHUNK 2048
#define NREP 8          // atomic-contention replication factor
#define NSEG1 4         // split-K segments for GEMM1
#define KSEG1 360       // K per segment (4*360 = 1440 >= 1433)

// ---------------- init (zeros replicated counters) ----------------
__global__ void k_init_cnt(int* __restrict__ cnt_r, int n) {
    int i = blockIdx.x * 256 + threadIdx.x;
    if (i < n) cnt_r[i] = 0;
}

// ---------------- degree count, 8-way replicated ----------------
__global__ void k_count(const int* __restrict__ edges, int* __restrict__ cnt_r,
                        int E, int N) {
    int e = blockIdx.x * 256 + threadIdx.x;
    if (e < E) atomicAdd(&cnt_r[(blockIdx.x & (NREP - 1)) * N + edges[E + e]], 1);
}

// ---------------- scan (3-phase exclusive prefix over summed cnt -> rs) ------
__global__ void k_scan1(const int* __restrict__ cnt_r, int* __restrict__ rs,
                        int* __restrict__ bsum, int N) {
    __shared__ int sh[256];
    int tid = threadIdx.x;
    int base = blockIdx.x * SCAN_CHUNK + tid * 8;
    int v[8];
    int s = 0;
#pragma unroll
    for (int u = 0; u < 8; ++u) {
        int idx = base + u;
        int t = 0;
        if (idx < N) {
#pragma unroll
            for (int r = 0; r < NREP; ++r) t += cnt_r[r * N + idx];
        }
        v[u] = t;
        s += t;
    }
    sh[tid] = s;
    __syncthreads();
    for (int off = 1; off < 256; off <<= 1) {
        int y = 0;
        if (tid >= off) y = sh[tid - off];
        __syncthreads();
        sh[tid] += y;
        __syncthreads();
    }
    int run = sh[tid] - s;
#pragma unroll
    for (int u = 0; u < 8; ++u) {
        int idx = base + u;
        if (idx < N) rs[idx] = run;
        run += v[u];
    }
    if (tid == 255) bsum[blockIdx.x] = sh[255];
}

__global__ void k_scan2(const int* __restrict__ bsum, int* __restrict__ boff, int NB) {
    if (blockIdx.x == 0 && threadIdx.x == 0) {
        int r = 0;
        for (int b = 0; b < NB; ++b) { int t = bsum[b]; boff[b] = r; r += t; }
    }
}

// finalize rs, build per-replica cursors, total cnt, dinv
__global__ void k_scan3(int* __restrict__ rs, int* __restrict__ cursor_r,
                        const int* __restrict__ cnt_r, int* __restrict__ cnt,
                        float* __restrict__ dinv, const int* __restrict__ boff, int N) {
    int i = blockIdx.x * 256 + threadIdx.x;
    if (i < N) {
        int run = rs[i] + boff[i / SCAN_CHUNK];
        rs[i] = run;
        int total = 0;
#pragma unroll
        for (int r = 0; r < NREP; ++r) {
            cursor_r[r * N + i] = run;
            int c = cnt_r[r * N + i];
            run += c;
            total += c;
        }
        cnt[i] = total;
        dinv[i] = rsqrtf((float)total + 1.0f);   // +1 self loop
    }
}

// ---------------- CSR fill (replica matches k_count's: same e -> same block) -
__global__ void k_fill(const int* __restrict__ edges, int* __restrict__ cursor_r,
                       int* __restrict__ col, int E, int N) {
    int e = blockIdx.x * 256 + threadIdx.x;
    if (e < E) {
        int d = edges[E + e];
        int s = edges[e];
        int pos = atomicAdd(&cursor_r[(blockIdx.x & (NREP - 1)) * N + d], 1);
        col[pos] = s;
    }
}

// ---------------- GEMM1 as register-resident GEMV ----------------------------
// Each lane owns ONE output row (acc[16] in VGPRs). W goes through the scalar
// path (k is blockIdx/loop-uniform -> s_load + v_fma with SGPR operand).
// Rows are assigned strided-by-4 with fixed parity per wave so that
// (row*1433 + k) mod 4 is wave-uniform -> per-lane float4 x-loads are 16B
// aligned after a uniform head shift. No LDS, no barriers, no shuffles.
// Grid: x = rowgroup(256 rows)*4 + parity, y = K-segment (NSEG1).
__device__ __forceinline__ void fma16(float acc[16], float xm,
                                      const float* __restrict__ wr) {
    const float4* w4 = (const float4*)wr;
    float4 w0 = w4[0], w1 = w4[1], w2 = w4[2], w3 = w4[3];
    acc[0]  = fmaf(xm, w0.x, acc[0]);  acc[1]  = fmaf(xm, w0.y, acc[1]);
    acc[2]  = fmaf(xm, w0.z, acc[2]);  acc[3]  = fmaf(xm, w0.w, acc[3]);
    acc[4]  = fmaf(xm, w1.x, acc[4]);  acc[5]  = fmaf(xm, w1.y, acc[5]);
    acc[6]  = fmaf(xm, w1.z, acc[6]);  acc[7]  = fmaf(xm, w1.w, acc[7]);
    acc[8]  = fmaf(xm, w2.x, acc[8]);  acc[9]  = fmaf(xm, w2.y, acc[9]);
    acc[10] = fmaf(xm, w2.z, acc[10]); acc[11] = fmaf(xm, w2.w, acc[11]);
    acc[12] = fmaf(xm, w3.x, acc[12]); acc[13] = fmaf(xm, w3.y, acc[13]);
    acc[14] = fmaf(xm, w3.z, acc[14]); acc[15] = fmaf(xm, w3.w, acc[15]);
}

__global__ __launch_bounds__(64) void k_gemv1(const float* __restrict__ x,
                                              const float* __restrict__ W,
                                              float* __restrict__ gpart, int N) {
    const int g   = blockIdx.x;         // rowgroup*4 + parity
    const int seg = blockIdx.y;         // 0..NSEG1-1
    const int par = g & 3;
    const int l   = threadIdx.x;        // 0..63
    int row = (g >> 2) * 256 + par + 4 * l;
    const bool ok = row < N;
    if (!ok) row = ((N - 1 - par) & ~3) + par;   // clamp, parity-preserving

    const int k0 = seg * KSEG1;
    const int k1 = min(k0 + KSEG1, F_IN);
    // 1433 % 4 == 1  =>  (row*1433 + k) % 4 == (par + k) % 4  (wave-uniform)
    const int sh = (4 - ((par + k0) & 3)) & 3;   // head length to alignment
    const float* xr = x + (long)row * F_IN;

    float acc[16];
#pragma unroll
    for (int j = 0; j < 16; ++j) acc[j] = 0.f;

    // head (uniform trip count 0..3, scalar x loads)
    for (int m = 0; m < sh; ++m) {
        float xv = xr[k0 + m];
        fma16(acc, xv, W + (k0 + m) * 16);
    }

    const int kb = k0 + sh;
    const int nfull = (k1 - kb) >> 2;
#pragma unroll 2
    for (int c = 0; c < nfull; ++c) {
        const int k = kb + (c << 2);
        const float4 xv = *(const float4*)(xr + k);  // 16B aligned by construction
        const float* wr = W + k * 16;
        fma16(acc, xv.x, wr);
        fma16(acc, xv.y, wr + 16);
        fma16(acc, xv.z, wr + 32);
        fma16(acc, xv.w, wr + 48);
    }

    // tail (uniform trip count 0..3)
    for (int k = kb + (nfull << 2); k < k1; ++k) {
        float xv = xr[k];
        fma16(acc, xv, W + k * 16);
    }

    if (ok) {
        float4* o = (float4*)(gpart + ((long)seg * N + row) * 16);
        o[0] = make_float4(acc[0],  acc[1],  acc[2],  acc[3]);
        o[1] = make_float4(acc[4],  acc[5],  acc[6],  acc[7]);
        o[2] = make_float4(acc[8],  acc[9],  acc[10], acc[11]);
        o[3] = make_float4(acc[12], acc[13], acc[14], acc[15]);
    }
}

// ---------------- reduce partials: g = dinv[row] * sum_seg gpart -------------
__global__ __launch_bounds__(256) void k_greduce(const float* __restrict__ gpart,
                                                 const float* __restrict__ dinv,
                                                 float* __restrict__ g, int N, int nseg) {
    int i4 = blockIdx.x * 256 + threadIdx.x;
    if (i4 >= N * 4) return;
    const float4* gp = (const float4*)gpart;
    float4 s = gp[i4];
    for (int p = 1; p < nseg; ++p) {
        float4 t = gp[(long)p * N * 4 + i4];
        s.x += t.x; s.y += t.y; s.z += t.z; s.w += t.w;
    }
    float d = dinv[i4 >> 2];
    s.x *= d; s.y *= d; s.z *= d; s.w *= d;
    ((float4*)g)[i4] = s;
}

// ---------------- gather layer1: x1 = relu(dinv*(sum g[src] + g[self]) + b1) --
__global__ __launch_bounds__(256) void k_gather1(const int* __restrict__ col,
                                                 const int* __restrict__ rs,
                                                 const int* __restrict__ cnt,
                                                 const float* __restrict__ g,
                                                 const float* __restrict__ dinv,
                                                 const float* __restrict__ b1,
                                                 float* __restrict__ x1, int N) {
    int node = blockIdx.x * 4 + (threadIdx.x >> 6);
    if (node >= N) return;
    int lane = threadIdx.x & 63;
    int q = lane >> 4;   // neighbor slot 0..3
    int j = lane & 15;   // feature
    int start = rs[node];
    int c = cnt[node];
    float acc = 0.f;
    for (int p = q; p < c; p += 4) {
        int s = col[start + p];
        acc += g[(long)s * F1 + j];
    }
    acc += __shfl_down(acc, 32, 64);
    acc += __shfl_down(acc, 16, 64);
    if (lane < 16) {
        float v = dinv[node] * (acc + g[(long)node * F1 + j]) + b1[j];
        x1[(long)node * F1 + j] = fmaxf(v, 0.f);
    }
}

// ---------------- GEMM2: g2 = dinv * (x1 @ W2), padded to 8 cols -------------
__global__ __launch_bounds__(256) void k_gemm2(const float* __restrict__ x1,
                                               const float* __restrict__ W2,
                                               const float* __restrict__ dinv,
                                               float* __restrict__ g2, int N) {
    int i = blockIdx.x * 256 + threadIdx.x;
    if (i >= N) return;
    const float4* xr = (const float4*)(x1 + (long)i * F1);
    float4 a0 = xr[0], a1 = xr[1], a2 = xr[2], a3 = xr[3];
    float xv[F1] = {a0.x, a0.y, a0.z, a0.w, a1.x, a1.y, a1.z, a1.w,
                    a2.x, a2.y, a2.z, a2.w, a3.x, a3.y, a3.z, a3.w};
    float acc[F2];
#pragma unroll
    for (int j = 0; j < F2; ++j) acc[j] = 0.f;
#pragma unroll
    for (int k = 0; k < F1; ++k) {
#pragma unroll
        for (int j = 0; j < F2; ++j) acc[j] = fmaf(xv[k], W2[k * F2 + j], acc[j]);
    }
    float d = dinv[i];
    float4* out = (float4*)(g2 + (long)i * 8);
    out[0] = make_float4(d * acc[0], d * acc[1], d * acc[2], d * acc[3]);
    out[1] = make_float4(d * acc[4], d * acc[5], d * acc[6], 0.f);
}

// ---------------- gather layer2 + bias + log_softmax -> d_out ----------------
__global__ __launch_bounds__(256) void k_gather2(const int* __restrict__ col,
                                                 const int* __restrict__ rs,
                                                 const int* __restrict__ cnt,
                                                 const float* __restrict__ g2,
                                                 const float* __restrict__ dinv,
                                                 const float* __restrict__ b2,
                                                 float* __restrict__ out, int N) {
    int node = blockIdx.x * 4 + (threadIdx.x >> 6);
    if (node >= N) return;
    int lane = threadIdx.x & 63;
    int q = lane >> 3;  // neighbor slot 0..7
    int j = lane & 7;   // feature 0..7 (7 = pad)
    int start = rs[node];
    int c = cnt[node];
    float acc = 0.f;
    for (int p = q; p < c; p += 8) {
        int s = col[start + p];
        acc += g2[(long)s * 8 + j];
    }
    acc += __shfl_down(acc, 32, 64);
    acc += __shfl_down(acc, 16, 64);
    acc += __shfl_down(acc, 8, 64);
    if (lane < 8) {
        float vv = -INFINITY;
        if (j < F2)
            vv = dinv[node] * (acc + g2[(long)node * 8 + j]) + b2[j];
        float m = vv;
        m = fmaxf(m, __shfl_xor(m, 1, 64));
        m = fmaxf(m, __shfl_xor(m, 2, 64));
        m = fmaxf(m, __shfl_xor(m, 4, 64));
        float e = (j < F2) ? expf(vv - m) : 0.f;
        e += __shfl_xor(e, 1, 64);
        e += __shfl_xor(e, 2, 64);
        e += __shfl_xor(e, 4, 64);
        if (j < F2)
            out[(long)node * F2 + j] = vv - m - logf(e);
    }
}

extern "C" void kernel_launch(void* const* d_in, const int* in_sizes, int n_in,
                              void* d_out, int out_size, void* d_ws, size_t ws_size,
                              hipStream_t stream) {
    const float* x     = (const float*)d_in[0];
    const int*   edges = (const int*)d_in[1];
    const float* W1    = (const float*)d_in[2];
    const float* b1    = (const float*)d_in[3];
    const float* W2    = (const float*)d_in[4];
    const float* b2    = (const float*)d_in[5];
    float* outp = (float*)d_out;

    int N = in_sizes[0] / F_IN;       // 50000
    int E = in_sizes[1] / 2;          // 1600000
    int NB = (N + SCAN_CHUNK - 1) / SCAN_CHUNK;

    char* ws = (char*)d_ws;
    size_t o = 0;
    auto alloc = [&](size_t bytes) { size_t r = o; o += (bytes + 255) & ~(size_t)255; return r; };
    int*   cnt_r    = (int*)  (ws + alloc((size_t)NREP * N * 4));
    int*   cursor_r = (int*)  (ws + alloc((size_t)NREP * N * 4));
    int*   cnt      = (int*)  (ws + alloc((size_t)N * 4));
    int*   rs       = (int*)  (ws + alloc((size_t)N * 4));
    float* dinv     = (float*)(ws + alloc((size_t)N * 4));
    int*   bsum     = (int*)  (ws + alloc((size_t)NB * 4));
    int*   boff     = (int*)  (ws + alloc((size_t)NB * 4));
    int*   col      = (int*)  (ws + alloc((size_t)E * 4));
    float* g        = (float*)(ws + alloc((size_t)N * F1 * 4));
    float* x1       = (float*)(ws + alloc((size_t)N * F1 * 4));
    float* g2       = (float*)(ws + alloc((size_t)N * 8 * 4));
    float* gpart    = (float*)(ws + alloc((size_t)NSEG1 * N * F1 * 4));
    (void)n_in; (void)out_size; (void)ws_size;

    int gN256 = (N + 255) / 256;
    int gE256 = (E + 255) / 256;

    k_init_cnt<<<(NREP * N + 255) / 256, 256, 0, stream>>>(cnt_r, NREP * N);
    k_count<<<gE256, 256, 0, stream>>>(edges, cnt_r, E, N);
    k_scan1<<<NB, 256, 0, stream>>>(cnt_r, rs, bsum, N);
    k_scan2<<<1, 64, 0, stream>>>(bsum, boff, NB);
    k_scan3<<<gN256, 256, 0, stream>>>(rs, cursor_r, cnt_r, cnt, dinv, boff, N);
    k_fill<<<gE256, 256, 0, stream>>>(edges, cursor_r, col, E, N);

    // GEMM1: 1-wave blocks, 64 rows/block (strided by 4, fixed parity), 4 K-segments
    int NG = (N + 255) / 256;                    // 256-row supergroups
    dim3 g1(NG * 4, NSEG1);
    k_gemv1<<<g1, 64, 0, stream>>>(x, W1, gpart, N);
    k_greduce<<<(N * 4 + 255) / 256, 256, 0, stream>>>(gpart, dinv, g, N, NSEG1);
    k_gather1<<<(N + 3) / 4, 256, 0, stream>>>(col, rs, cnt, g, dinv, b1, x1, N);
    k_gemm2<<<gN256, 256, 0, stream>>>(x1, W2, dinv, g2, N);
    k_gather2<<<(N + 3) / 4, 256, 0, stream>>>(col, rs, cnt, g2, dinv, b2, outp, N);
}

// Round 2
// 676.585 us; speedup vs baseline: 1.2420x; 1.0990x over previous
//
#include <hip/hip_runtime.h>
#include <math.h>

// Problem constants (reference: N_NODES=50000, F_in=1433, F1=16, F2=7)
#define F_IN 1433
#define F1 16
#define F2 7
#define SCAN_CHUNK 2048
#define NREP 8          // atomic-contention replication factor
#define NSEG1 4         // split-K segments for GEMM1
#define KSEG1 360       // K per segment (4*360 = 1440 >= 1433)

// ---------------- init (zeros replicated counters) ----------------
__global__ void k_init_cnt(int* __restrict__ cnt_r, int n) {
    int i = blockIdx.x * 256 + threadIdx.x;
    if (i < n) cnt_r[i] = 0;
}

// ---------------- degree count, 8-way replicated ----------------
__global__ void k_count(const int* __restrict__ edges, int* __restrict__ cnt_r,
                        int E, int N) {
    int e = blockIdx.x * 256 + threadIdx.x;
    if (e < E) atomicAdd(&cnt_r[(blockIdx.x & (NREP - 1)) * N + edges[E + e]], 1);
}

// ---------------- scan (3-phase exclusive prefix over summed cnt -> rs) ------
__global__ void k_scan1(const int* __restrict__ cnt_r, int* __restrict__ rs,
                        int* __restrict__ bsum, int N) {
    __shared__ int sh[256];
    int tid = threadIdx.x;
    int base = blockIdx.x * SCAN_CHUNK + tid * 8;
    int v[8];
    int s = 0;
#pragma unroll
    for (int u = 0; u < 8; ++u) {
        int idx = base + u;
        int t = 0;
        if (idx < N) {
#pragma unroll
            for (int r = 0; r < NREP; ++r) t += cnt_r[r * N + idx];
        }
        v[u] = t;
        s += t;
    }
    sh[tid] = s;
    __syncthreads();
    for (int off = 1; off < 256; off <<= 1) {
        int y = 0;
        if (tid >= off) y = sh[tid - off];
        __syncthreads();
        sh[tid] += y;
        __syncthreads();
    }
    int run = sh[tid] - s;
#pragma unroll
    for (int u = 0; u < 8; ++u) {
        int idx = base + u;
        if (idx < N) rs[idx] = run;
        run += v[u];
    }
    if (tid == 255) bsum[blockIdx.x] = sh[255];
}

__global__ void k_scan2(const int* __restrict__ bsum, int* __restrict__ boff, int NB) {
    if (blockIdx.x == 0 && threadIdx.x == 0) {
        int r = 0;
        for (int b = 0; b < NB; ++b) { int t = bsum[b]; boff[b] = r; r += t; }
    }
}

// finalize rs, build per-replica cursors, total cnt, dinv
__global__ void k_scan3(int* __restrict__ rs, int* __restrict__ cursor_r,
                        const int* __restrict__ cnt_r, int* __restrict__ cnt,
                        float* __restrict__ dinv, const int* __restrict__ boff, int N) {
    int i = blockIdx.x * 256 + threadIdx.x;
    if (i < N) {
        int run = rs[i] + boff[i / SCAN_CHUNK];
        rs[i] = run;
        int total = 0;
#pragma unroll
        for (int r = 0; r < NREP; ++r) {
            cursor_r[r * N + i] = run;
            int c = cnt_r[r * N + i];
            run += c;
            total += c;
        }
        cnt[i] = total;
        dinv[i] = rsqrtf((float)total + 1.0f);   // +1 self loop
    }
}

// ---------------- CSR fill (replica matches k_count's: same e -> same block) -
__global__ void k_fill(const int* __restrict__ edges, int* __restrict__ cursor_r,
                       int* __restrict__ col, int E, int N) {
    int e = blockIdx.x * 256 + threadIdx.x;
    if (e < E) {
        int d = edges[E + e];
        int s = edges[e];
        int pos = atomicAdd(&cursor_r[(blockIdx.x & (NREP - 1)) * N + d], 1);
        col[pos] = s;
    }
}

// ---------------- GEMM1 as register-resident GEMV ----------------------------
// Each lane owns ONE output row (acc[16] in VGPRs); W on the scalar path.
// Rows strided-by-4 with fixed parity per wave -> (row*1433+k) mod 4 is
// wave-uniform -> per-lane float4 x-loads are 16B aligned after a uniform
// head shift. K processed in 32-wide groups with a register double-buffer:
// next group's 8 float4 loads (8KB/wave in flight) issue before the current
// group's 512 FMAs -> memory-level parallelism to saturate HBM.
__device__ __forceinline__ void fma16(float acc[16], float xm,
                                      const float* __restrict__ wr) {
    const float4* w4 = (const float4*)wr;
    float4 w0 = w4[0], w1 = w4[1], w2 = w4[2], w3 = w4[3];
    acc[0]  = fmaf(xm, w0.x, acc[0]);  acc[1]  = fmaf(xm, w0.y, acc[1]);
    acc[2]  = fmaf(xm, w0.z, acc[2]);  acc[3]  = fmaf(xm, w0.w, acc[3]);
    acc[4]  = fmaf(xm, w1.x, acc[4]);  acc[5]  = fmaf(xm, w1.y, acc[5]);
    acc[6]  = fmaf(xm, w1.z, acc[6]);  acc[7]  = fmaf(xm, w1.w, acc[7]);
    acc[8]  = fmaf(xm, w2.x, acc[8]);  acc[9]  = fmaf(xm, w2.y, acc[9]);
    acc[10] = fmaf(xm, w2.z, acc[10]); acc[11] = fmaf(xm, w2.w, acc[11]);
    acc[12] = fmaf(xm, w3.x, acc[12]); acc[13] = fmaf(xm, w3.y, acc[13]);
    acc[14] = fmaf(xm, w3.z, acc[14]); acc[15] = fmaf(xm, w3.w, acc[15]);
}

__device__ __forceinline__ void fma_grp32(float acc[16], const float4 cur[8],
                                          const float* __restrict__ W, int kbase) {
#pragma unroll
    for (int i = 0; i < 8; ++i) {
        const float* wr = W + (kbase + i * 4) * 16;
        fma16(acc, cur[i].x, wr);
        fma16(acc, cur[i].y, wr + 16);
        fma16(acc, cur[i].z, wr + 32);
        fma16(acc, cur[i].w, wr + 48);
    }
}

__global__ __launch_bounds__(64) void k_gemv1(const float* __restrict__ x,
                                              const float* __restrict__ W,
                                              float* __restrict__ gpart, int N) {
    const int g   = blockIdx.x;         // rowgroup*4 + parity
    const int seg = blockIdx.y;         // 0..NSEG1-1
    const int par = g & 3;
    const int l   = threadIdx.x;        // 0..63
    int row = (g >> 2) * 256 + par + 4 * l;
    const bool ok = row < N;
    if (!ok) row = ((N - 1 - par) & ~3) + par;   // clamp, parity-preserving

    const int k0 = seg * KSEG1;
    const int k1 = min(k0 + KSEG1, F_IN);
    // 1433 % 4 == 1  =>  (row*1433 + k) % 4 == (par + k) % 4  (wave-uniform)
    const int sh = (4 - ((par + k0) & 3)) & 3;   // head length to alignment
    const float* xr = x + (long)row * F_IN;

    float acc[16];
#pragma unroll
    for (int j = 0; j < 16; ++j) acc[j] = 0.f;

    // head (uniform trip count 0..3, scalar x loads)
    for (int m = 0; m < sh; ++m) {
        float xv = xr[k0 + m];
        fma16(acc, xv, W + (k0 + m) * 16);
    }

    const int kb   = k0 + sh;
    const int kcnt = k1 - kb;
    const int ng   = kcnt >> 5;          // 32-k groups
    const float4* xp = (const float4*)(xr + kb);   // 16B aligned by construction

    if (ng > 0) {
        float4 cur[8];
#pragma unroll
        for (int i = 0; i < 8; ++i) cur[i] = xp[i];
        for (int c = 0; c < ng - 1; ++c) {
            float4 nxt[8];
            const float4* q = xp + (c + 1) * 8;
#pragma unroll
            for (int i = 0; i < 8; ++i) nxt[i] = q[i];   // prefetch next group
            fma_grp32(acc, cur, W, kb + c * 32);
#pragma unroll
            for (int i = 0; i < 8; ++i) cur[i] = nxt[i];
        }
        fma_grp32(acc, cur, W, kb + (ng - 1) * 32);      // peeled last group
    }

    // 4-k remainder groups (uniform trip count 0..7)
    const int k4b = kb + (ng << 5);
    const int n4  = (k1 - k4b) >> 2;
    for (int c = 0; c < n4; ++c) {
        const int k = k4b + (c << 2);
        const float4 xv = *(const float4*)(xr + k);
        const float* wr = W + k * 16;
        fma16(acc, xv.x, wr);
        fma16(acc, xv.y, wr + 16);
        fma16(acc, xv.z, wr + 32);
        fma16(acc, xv.w, wr + 48);
    }

    // scalar tail (uniform trip count 0..3)
    for (int k = k4b + (n4 << 2); k < k1; ++k) {
        float xv = xr[k];
        fma16(acc, xv, W + k * 16);
    }

    if (ok) {
        float4* o = (float4*)(gpart + ((long)seg * N + row) * 16);
        o[0] = make_float4(acc[0],  acc[1],  acc[2],  acc[3]);
        o[1] = make_float4(acc[4],  acc[5],  acc[6],  acc[7]);
        o[2] = make_float4(acc[8],  acc[9],  acc[10], acc[11]);
        o[3] = make_float4(acc[12], acc[13], acc[14], acc[15]);
    }
}

// ---------------- reduce partials: g = dinv[row] * sum_seg gpart -------------
__global__ __launch_bounds__(256) void k_greduce(const float* __restrict__ gpart,
                                                 const float* __restrict__ dinv,
                                                 float* __restrict__ g, int N, int nseg) {
    int i4 = blockIdx.x * 256 + threadIdx.x;
    if (i4 >= N * 4) return;
    const float4* gp = (const float4*)gpart;
    float4 s = gp[i4];
    for (int p = 1; p < nseg; ++p) {
        float4 t = gp[(long)p * N * 4 + i4];
        s.x += t.x; s.y += t.y; s.z += t.z; s.w += t.w;
    }
    float d = dinv[i4 >> 2];
    s.x *= d; s.y *= d; s.z *= d; s.w *= d;
    ((float4*)g)[i4] = s;
}

// ---------------- gather layer1: x1 = relu(dinv*(sum g[src] + g[self]) + b1) --
__global__ __launch_bounds__(256) void k_gather1(const int* __restrict__ col,
                                                 const int* __restrict__ rs,
                                                 const int* __restrict__ cnt,
                                                 const float* __restrict__ g,
                                                 const float* __restrict__ dinv,
                                                 const float* __restrict__ b1,
                                                 float* __restrict__ x1, int N) {
    int node = blockIdx.x * 4 + (threadIdx.x >> 6);
    if (node >= N) return;
    int lane = threadIdx.x & 63;
    int q = lane >> 4;   // neighbor slot 0..3
    int j = lane & 15;   // feature
    int start = rs[node];
    int c = cnt[node];
    float acc = 0.f;
    int p = q;
    if (p < c) {
        int s = col[start + p];
        for (;;) {
            int pn = p + 4;
            bool more = pn < c;
            int sn = 0;
            if (more) sn = col[start + pn];      // prefetch next index
            acc += g[(long)s * F1 + j];
            if (!more) break;
            s = sn; p = pn;
        }
    }
    acc += __shfl_down(acc, 32, 64);
    acc += __shfl_down(acc, 16, 64);
    if (lane < 16) {
        float v = dinv[node] * (acc + g[(long)node * F1 + j]) + b1[j];
        x1[(long)node * F1 + j] = fmaxf(v, 0.f);
    }
}

// ---------------- GEMM2: g2 = dinv * (x1 @ W2), padded to 8 cols -------------
__global__ __launch_bounds__(256) void k_gemm2(const float* __restrict__ x1,
                                               const float* __restrict__ W2,
                                               const float* __restrict__ dinv,
                                               float* __restrict__ g2, int N) {
    int i = blockIdx.x * 256 + threadIdx.x;
    if (i >= N) return;
    const float4* xr = (const float4*)(x1 + (long)i * F1);
    float4 a0 = xr[0], a1 = xr[1], a2 = xr[2], a3 = xr[3];
    float xv[F1] = {a0.x, a0.y, a0.z, a0.w, a1.x, a1.y, a1.z, a1.w,
                    a2.x, a2.y, a2.z, a2.w, a3.x, a3.y, a3.z, a3.w};
    float acc[F2];
#pragma unroll
    for (int j = 0; j < F2; ++j) acc[j] = 0.f;
#pragma unroll
    for (int k = 0; k < F1; ++k) {
#pragma unroll
        for (int j = 0; j < F2; ++j) acc[j] = fmaf(xv[k], W2[k * F2 + j], acc[j]);
    }
    float d = dinv[i];
    float4* out = (float4*)(g2 + (long)i * 8);
    out[0] = make_float4(d * acc[0], d * acc[1], d * acc[2], d * acc[3]);
    out[1] = make_float4(d * acc[4], d * acc[5], d * acc[6], 0.f);
}

// ---------------- gather layer2 + bias + log_softmax -> d_out ----------------
__global__ __launch_bounds__(256) void k_gather2(const int* __restrict__ col,
                                                 const int* __restrict__ rs,
                                                 const int* __restrict__ cnt,
                                                 const float* __restrict__ g2,
                                                 const float* __restrict__ dinv,
                                                 const float* __restrict__ b2,
                                                 float* __restrict__ out, int N) {
    int node = blockIdx.x * 4 + (threadIdx.x >> 6);
    if (node >= N) return;
    int lane = threadIdx.x & 63;
    int q = lane >> 3;  // neighbor slot 0..7
    int j = lane & 7;   // feature 0..7 (7 = pad)
    int start = rs[node];
    int c = cnt[node];
    float acc = 0.f;
    int p = q;
    if (p < c) {
        int s = col[start + p];
        for (;;) {
            int pn = p + 8;
            bool more = pn < c;
            int sn = 0;
            if (more) sn = col[start + pn];      // prefetch next index
            acc += g2[(long)s * 8 + j];
            if (!more) break;
            s = sn; p = pn;
        }
    }
    acc += __shfl_down(acc, 32, 64);
    acc += __shfl_down(acc, 16, 64);
    acc += __shfl_down(acc, 8, 64);
    if (lane < 8) {
        float vv = -INFINITY;
        if (j < F2)
            vv = dinv[node] * (acc + g2[(long)node * 8 + j]) + b2[j];
        float m = vv;
        m = fmaxf(m, __shfl_xor(m, 1, 64));
        m = fmaxf(m, __shfl_xor(m, 2, 64));
        m = fmaxf(m, __shfl_xor(m, 4, 64));
        float e = (j < F2) ? expf(vv - m) : 0.f;
        e += __shfl_xor(e, 1, 64);
        e += __shfl_xor(e, 2, 64);
        e += __shfl_xor(e, 4, 64);
        if (j < F2)
            out[(long)node * F2 + j] = vv - m - logf(e);
    }
}

extern "C" void kernel_launch(void* const* d_in, const int* in_sizes, int n_in,
                              void* d_out, int out_size, void* d_ws, size_t ws_size,
                              hipStream_t stream) {
    const float* x     = (const float*)d_in[0];
    const int*   edges = (const int*)d_in[1];
    const float* W1    = (const float*)d_in[2];
    const float* b1    = (const float*)d_in[3];
    const float* W2    = (const float*)d_in[4];
    const float* b2    = (const float*)d_in[5];
    float* outp = (float*)d_out;

    int N = in_sizes[0] / F_IN;       // 50000
    int E = in_sizes[1] / 2;          // 1600000
    int NB = (N + SCAN_CHUNK - 1) / SCAN_CHUNK;

    char* ws = (char*)d_ws;
    size_t o = 0;
    auto alloc = [&](size_t bytes) { size_t r = o; o += (bytes + 255) & ~(size_t)255; return r; };
    int*   cnt_r    = (int*)  (ws + alloc((size_t)NREP * N * 4));
    int*   cursor_r = (int*)  (ws + alloc((size_t)NREP * N * 4));
    int*   cnt      = (int*)  (ws + alloc((size_t)N * 4));
    int*   rs       = (int*)  (ws + alloc((size_t)N * 4));
    float* dinv     = (float*)(ws + alloc((size_t)N * 4));
    int*   bsum     = (int*)  (ws + alloc((size_t)NB * 4));
    int*   boff     = (int*)  (ws + alloc((size_t)NB * 4));
    int*   col      = (int*)  (ws + alloc((size_t)E * 4));
    float* g        = (float*)(ws + alloc((size_t)N * F1 * 4));
    float* x1       = (float*)(ws + alloc((size_t)N * F1 * 4));
    float* g2       = (float*)(ws + alloc((size_t)N * 8 * 4));
    float* gpart    = (float*)(ws + alloc((size_t)NSEG1 * N * F1 * 4));
    (void)n_in; (void)out_size; (void)ws_size;

    int gN256 = (N + 255) / 256;
    int gE256 = (E + 255) / 256;

    k_init_cnt<<<(NREP * N + 255) / 256, 256, 0, stream>>>(cnt_r, NREP * N);
    k_count<<<gE256, 256, 0, stream>>>(edges, cnt_r, E, N);
    k_scan1<<<NB, 256, 0, stream>>>(cnt_r, rs, bsum, N);
    k_scan2<<<1, 64, 0, stream>>>(bsum, boff, NB);
    k_scan3<<<gN256, 256, 0, stream>>>(rs, cursor_r, cnt_r, cnt, dinv, boff, N);
    k_fill<<<gE256, 256, 0, stream>>>(edges, cursor_r, col, E, N);

    // GEMM1: 1-wave blocks, 64 rows/block (strided by 4, fixed parity), 4 K-segments
    int NG = (N + 255) / 256;                    // 256-row supergroups
    dim3 g1(NG * 4, NSEG1);
    k_gemv1<<<g1, 64, 0, stream>>>(x, W1, gpart, N);
    k_greduce<<<(N * 4 + 255) / 256, 256, 0, stream>>>(gpart, dinv, g, N, NSEG1);
    k_gather1<<<(N + 3) / 4, 256, 0, stream>>>(col, rs, cnt, g, dinv, b1, x1, N);
    k_gemm2<<<gN256, 256, 0, stream>>>(x1, W2, dinv, g2, N);
    k_gather2<<<(N + 3) / 4, 256, 0, stream>>>(col, rs, cnt, g2, dinv, b2, outp, N);
}